// Round 14
// baseline (429.157 us; speedup 1.0000x reference)
//
#include <hip/hip_runtime.h>

typedef short short8 __attribute__((ext_vector_type(8)));
typedef float f32x4 __attribute__((ext_vector_type(4)));
typedef float f32x16 __attribute__((ext_vector_type(16)));
typedef unsigned int uint2v __attribute__((ext_vector_type(2)));

// ---------- helpers ----------
static __device__ __forceinline__ ushort f2bf(float f){
  union { float f; uint u; } cv; cv.f = f;
  uint u = cv.u;
  uint r = (u + 0x7fffu + ((u >> 16) & 1u)) >> 16;
  return (ushort)r;
}
static __device__ __forceinline__ float bf2f(ushort h){
  union { uint u; float f; } cv; cv.u = ((uint)h) << 16; return cv.f;
}
static __device__ __forceinline__ f32x4 mfma16(short8 a, short8 b, f32x4 c){
  return __builtin_amdgcn_mfma_f32_16x16x32_bf16(a, b, c, 0, 0, 0);
}
static __device__ __forceinline__ f32x16 mfma32(short8 a, short8 b, f32x16 c){
  return __builtin_amdgcn_mfma_f32_32x32x16_bf16(a, b, c, 0, 0, 0);
}
static __device__ __forceinline__ float ex2(float x){
  float r; asm("v_exp_f32 %0, %1" : "=v"(r) : "v"(x)); return r;
}
static __device__ __forceinline__ uint cvtpk(float lo, float hi){
  uint r; asm("v_cvt_pk_bf16_f32 %0, %1, %2" : "=v"(r) : "v"(lo), "v"(hi)); return r;
}
static __device__ __forceinline__ void glds16(const void* g, const void* l){
  __builtin_amdgcn_global_load_lds((const __attribute__((address_space(1))) void*)g,
                                   (__attribute__((address_space(3))) void*)l, 16, 0, 0);
}
static __device__ __forceinline__ void store_out(float* p, float v){ *p = v; }
static __device__ __forceinline__ void store_out(ushort* p, float v){ *p = f2bf(v); }
// bijective XCD-aware block swizzle (m204 form)
static __device__ __forceinline__ int xcd_swizzle(int flat, int nwg){
  int q = nwg >> 3, r = nwg & 7;
  int xcd = flat & 7, idx = flat >> 3;
  return (xcd < r) ? xcd * (q + 1) + idx : r * (q + 1) + (xcd - r) * q + idx;
}

// ---------- elementwise f32 -> bf16 ----------
__global__ void cvt_bf16_kernel(const float* __restrict__ x, ushort* __restrict__ y, int n4){
  int i = blockIdx.x * 256 + threadIdx.x;
  if (i < n4){
    float4 v = reinterpret_cast<const float4*>(x)[i];
    ushort4 o; o.x = f2bf(v.x); o.y = f2bf(v.y); o.z = f2bf(v.z); o.w = f2bf(v.w);
    reinterpret_cast<ushort4*>(y)[i] = o;
  }
}

// ---------- f32 partial sum: out = p0 + p1 ----------
__global__ void addk_kernel(const float* __restrict__ p0, const float* __restrict__ p1,
                            float* __restrict__ out, int n4){
  int i = blockIdx.x * 256 + threadIdx.x;
  if (i < n4){
    float4 a = reinterpret_cast<const float4*>(p0)[i];
    float4 b = reinterpret_cast<const float4*>(p1)[i];
    float4 o; o.x = a.x + b.x; o.y = a.y + b.y; o.z = a.z + b.z; o.w = a.w + b.w;
    reinterpret_cast<float4*>(out)[i] = o;
  }
}

// ---------- transpose + cast: W (K x N) f32 -> WT (N x K) bf16 ----------
__global__ void transpose_cvt_kernel(const float* __restrict__ W, ushort* __restrict__ WT, int K, int N){
  __shared__ float tile[32][33];
  int n0 = blockIdx.x * 32, k0 = blockIdx.y * 32;
  int tx = threadIdx.x, ty = threadIdx.y; // block (32,8)
  #pragma unroll
  for (int i = 0; i < 4; i++){ int r = ty + i * 8; tile[r][tx] = W[(size_t)(k0 + r) * N + n0 + tx]; }
  __syncthreads();
  #pragma unroll
  for (int i = 0; i < 4; i++){ int r = ty + i * 8; WT[(size_t)(n0 + r) * K + k0 + tx] = f2bf(tile[tx][r]); }
}

// ---------- concat qkv bias ----------
__global__ void bias_concat_kernel(const float* __restrict__ bq, const float* __restrict__ bk,
                                   const float* __restrict__ bv, float* __restrict__ out){
  int i = blockIdx.x * 256 + threadIdx.x;
  if (i < 6144) out[i] = (i < 4096) ? bq[i] : ((i < 5120) ? bk[i - 4096] : bv[i - 5120]);
}

// ---------- 256x256 8-phase GEMM (m201 template; offset + residency FIXED) ----------
// 8 waves 2Mx4N, per-wave 128x64 (acc f32x4[8][4], 16x16x32 MFMA). BK=64,
// 2 K-tiles per iteration = 8 phases. Group boundary (phi0/phi4):
//   STG next-half -> vmcnt(2) -> BARRIER -> mem-clobber -> reads -> MFMA -> barrier
// (counted vmcnt: retires all 8 stages of the tile about to be read, keeps the
// just-issued 2 in flight; never drains mid-loop). Other phases: reads issued
// before pre-MFMA barrier (resident since group barrier). 24 ds_read_b128/wave/
// K-tile (minimal). WAR: each half restaged >=4 barrier-phases after last read.
// Swizzle: source chunk c^(row&7), read pos (ks*4+lk)^(lm&7) (r9: 0 conflicts).
template<typename OutT>
__global__ __launch_bounds__(512, 1) void gemm8p_kernel(const ushort* __restrict__ A, const ushort* __restrict__ BT,
                                                        const float* __restrict__ bias, OutT* __restrict__ C,
                                                        int M, int N, int K, int klen){
  __shared__ __align__(16) ushort As[2][2][128 * 64];   // [buf][half(=wr)][row*64 + pos*8]
  __shared__ __align__(16) ushort Bs[2][2][128 * 64];   // [buf][half(=wc>>1)]
  const int nbx = N >> 8;
  const int nwg = nbx * (M >> 8);
  const int wg = xcd_swizzle(blockIdx.x, nwg);
  const int m0 = (wg / nbx) * 256, n0 = (wg % nbx) * 256;
  const int kb = blockIdx.y * klen;
  OutT* Cp = C + (size_t)blockIdx.y * M * N;
  const int tid = threadIdx.x, w = tid >> 6, l = tid & 63, lm = l & 15, lk = l >> 4;
  const int wr = w >> 2, wc = w & 3;
  const int bh = wc >> 1, brow = (wc & 1) * 64;   // B half / local row base
  const int sw = lm & 7;
  // staging: thread covers rows (tid>>3) and 64+(tid>>3) of a [128][64] half
  const int srow = tid >> 3, sch = tid & 7;
  const int sg = sch ^ (srow & 7);                // (64+srow)&7 == srow&7
  const int J = (klen >> 6) >> 1;                  // iterations, 2 K-tiles each

  // stage half H of matrix MAT (0=A rows m0+H*128.., 1=B rows n0+H*128..) of K-tile T into buf BUF
#define STG(MAT, H, T, BUF) do{                                                            \
    const ushort* _s = (MAT) ? BT : A;                                                     \
    const int _rb = ((MAT) ? n0 : m0) + (H) * 128;                                         \
    ushort* _d = (MAT) ? &Bs[BUF][H][0] : &As[BUF][H][0];                                  \
    glds16(_s + (size_t)(_rb + srow) * K + kb + (size_t)(T) * 64 + sg * 8,                 \
           _d + tid * 8);                                                                  \
    glds16(_s + (size_t)(_rb + 64 + srow) * K + kb + (size_t)(T) * 64 + sg * 8,            \
           _d + 4096 + tid * 8);                                                           \
  }while(0)

#define RD_AF(BUF, MH) do{                                                                 \
    _Pragma("unroll")                                                                      \
    for (int mi = 0; mi < 4; mi++)                                                         \
      _Pragma("unroll")                                                                    \
      for (int ks = 0; ks < 2; ks++)                                                       \
        af[mi][ks] = *(const short8*)&As[BUF][wr]                                          \
            [((MH) * 64 + mi * 16 + lm) * 64 + (((ks * 4 + lk) ^ sw) * 8)];                \
  }while(0)

#define RD_BF(DST, BUF, NH) do{                                                            \
    _Pragma("unroll")                                                                      \
    for (int ni = 0; ni < 2; ni++)                                                         \
      _Pragma("unroll")                                                                    \
      for (int ks = 0; ks < 2; ks++)                                                       \
        DST[ni][ks] = *(const short8*)&Bs[BUF][bh]                                         \
            [(brow + (NH) * 32 + ni * 16 + lm) * 64 + (((ks * 4 + lk) ^ sw) * 8)];         \
  }while(0)

#define MM(MH, NH, BF) do{                                                                 \
    __builtin_amdgcn_s_setprio(1);                                                        \
    _Pragma("unroll")                                                                      \
    for (int mi = 0; mi < 4; mi++)                                                         \
      _Pragma("unroll")                                                                    \
      for (int ni = 0; ni < 2; ni++)                                                       \
        _Pragma("unroll")                                                                  \
        for (int ks = 0; ks < 2; ks++)                                                     \
          acc[(MH)*4+mi][(NH)*2+ni] = mfma16(af[mi][ks], BF[ni][ks], acc[(MH)*4+mi][(NH)*2+ni]); \
    __builtin_amdgcn_s_setprio(0);                                                        \
  }while(0)

#define BAR() __builtin_amdgcn_s_barrier()
#define FENCE() asm volatile("" ::: "memory")

  f32x4 acc[8][4] = {};
  short8 af[4][2], bf01[2][2], bf23[2][2];
  // prologue: K-tile 0 -> buf0 (A-h0, B-h0, A-h1, B-h1) = 8 loads/thread
  STG(0, 0, 0, 0); STG(1, 0, 0, 0); STG(0, 1, 0, 0); STG(1, 1, 0, 0);
  for (int j = 0; j < J; j++){
    const int t0 = 2 * j;
    const bool lastit = (j == J - 1);
    // ===== K-tile t0 in buf0; stage K-tile t0+1 -> buf1 across phi0-3 =====
    // phi0: residency of buf0 established here (counted vmcnt + barrier)
    STG(0, 0, t0 + 1, 1);
    asm volatile("s_waitcnt vmcnt(2)" ::: "memory");
    BAR(); FENCE();
    RD_AF(0, 0); RD_BF(bf01, 0, 0);
    MM(0, 0, bf01);
    BAR();
    // phi1
    RD_BF(bf23, 0, 1);
    STG(1, 0, t0 + 1, 1);
    BAR(); MM(0, 1, bf23); BAR();
    // phi2
    RD_AF(0, 1);
    STG(0, 1, t0 + 1, 1);
    BAR(); MM(1, 1, bf23); BAR();
    // phi3
    STG(1, 1, t0 + 1, 1);
    BAR(); MM(1, 0, bf01); BAR();
    // ===== K-tile t0+1 in buf1; stage K-tile t0+2 -> buf0 across phi4-7 =====
    // phi4: residency of buf1 established here
    if (!lastit){ STG(0, 0, t0 + 2, 0); asm volatile("s_waitcnt vmcnt(2)" ::: "memory"); }
    else        { asm volatile("s_waitcnt vmcnt(0)" ::: "memory"); }
    BAR(); FENCE();
    RD_AF(1, 0); RD_BF(bf01, 1, 0);
    MM(0, 0, bf01);
    BAR();
    // phi5
    RD_BF(bf23, 1, 1);
    if (!lastit) STG(1, 0, t0 + 2, 0);
    BAR(); MM(0, 1, bf23); BAR();
    // phi6
    RD_AF(1, 1);
    if (!lastit) STG(0, 1, t0 + 2, 0);
    BAR(); MM(1, 1, bf23); BAR();
    // phi7
    if (!lastit) STG(1, 1, t0 + 2, 0);
    BAR(); MM(1, 0, bf01); BAR();
  }
#undef STG
#undef RD_AF
#undef RD_BF
#undef MM
#undef BAR
#undef FENCE
  // ---- epilogue: 16x16 C layout col=lm, row=lk*4+r ----
  #pragma unroll
  for (int mi = 0; mi < 8; mi++)
    #pragma unroll
    for (int ni = 0; ni < 4; ni++){
      int col = n0 + wc * 64 + ni * 16 + lm;
      float bb = bias ? bias[col] : 0.0f;
      #pragma unroll
      for (int r = 0; r < 4; r++){
        int row = m0 + wr * 128 + mi * 16 + lk * 4 + r;
        store_out(&Cp[(size_t)row * N + col], acc[mi][ni][r] + bb);
      }
    }
}

// ---------- RMSNorm + RoPE + relayout ----------
#define QSCL2 0.12752016f
__global__ __launch_bounds__(256) void norm_rope_kernel(const ushort* __restrict__ qkv,
    const float* __restrict__ cosT, const float* __restrict__ sinT,
    const float* __restrict__ qs, const float* __restrict__ ksc,
    ushort* __restrict__ qo, ushort* __restrict__ ko, ushort* __restrict__ vto){
  int slot = blockIdx.x * 4 + (threadIdx.x >> 6);
  int lane = threadIdx.x & 63;
  int row = slot / 48, c = slot % 48;      // row = b*S + s
  int b = row >> 11, s = row & 2047;
  size_t base = (size_t)row * 6144 + c * 128;
  float e1 = bf2f(qkv[base + lane]);
  float e2 = bf2f(qkv[base + lane + 64]);
  if (c < 40){
    float ss = e1 * e1 + e2 * e2;
    #pragma unroll
    for (int m = 1; m < 64; m <<= 1) ss += __shfl_xor(ss, m);
    float rs = rsqrtf(ss * (1.0f / 128.0f) + 1e-6f);
    const float* sc = (c < 32) ? qs : ksc;
    float n1 = e1 * rs * sc[lane], n2 = e2 * rs * sc[lane + 64];
    float c1 = cosT[s * 128 + lane],      s1 = sinT[s * 128 + lane];
    float c2 = cosT[s * 128 + lane + 64], s2 = sinT[s * 128 + lane + 64];
    float o1 = n1 * c1 - n2 * s1;
    float o2 = n2 * c2 + n1 * s2;
    if (c < 32){
      size_t ob = ((size_t)(b * 32 + c) * 2048 + s) * 128;
      qo[ob + lane] = f2bf(o1 * QSCL2); qo[ob + lane + 64] = f2bf(o2 * QSCL2);
    } else {
      int kv = c - 32;
      size_t ob = ((size_t)(b * 8 + kv) * 2048 + s) * 128;
      ko[ob + lane] = f2bf(o1); ko[ob + lane + 64] = f2bf(o2);
    }
  } else {
    int kv = c - 40;
    size_t ob = (size_t)(b * 8 + kv) * 128;
    vto[(ob + lane) * 2048 + s]      = f2bf(e1);
    vto[(ob + lane + 64) * 2048 + s] = f2bf(e2);
  }
}

// ---------- causal GQA flash attention: 32x32 MFMA, QBLK=128, KVBLK=64 ----------
__global__ __launch_bounds__(256, 2) void flash_kernel(const ushort* __restrict__ Q, const ushort* __restrict__ Kg,
    const ushort* __restrict__ VTg, ushort* __restrict__ ctx){
  __shared__ ushort Kl[2][64 * 128];
  __shared__ ushort Vl[2][128 * 64];
  const int bh = blockIdx.y, b = bh >> 5, h = bh & 31, kvh = h >> 2;
  const int bx = blockIdx.x;
  const int tid = threadIdx.x, w = tid >> 6, l = tid & 63;
  const int q31 = l & 31, hi = l >> 5, swz = q31 & 7;
  const ushort* Kbase = Kg  + (size_t)(b * 8 + kvh) * 2048 * 128;
  const ushort* Vbase = VTg + (size_t)(b * 8 + kvh) * 128 * 2048;
  const int krow = l >> 4, kcol = l & 15;
  const int vrow = l >> 3, vcol = l & 7;

  #define STAGE(KT, BS) do {                                                            \
    _Pragma("unroll")                                                                   \
    for (int i2 = 0; i2 < 4; i2++){                                                     \
      int i = w * 4 + i2; int row = i * 4 + krow;                                       \
      glds16(Kbase + (size_t)((KT) * 64 + row) * 128 + ((kcol ^ (row & 7)) * 8),        \
             &Kl[BS][i * 512]);                                                         \
    }                                                                                   \
    _Pragma("unroll")                                                                   \
    for (int j2 = 0; j2 < 4; j2++){                                                     \
      int j = w * 4 + j2; int row = j * 8 + vrow;                                       \
      glds16(Vbase + (size_t)row * 2048 + (KT) * 64 + ((vcol ^ (row & 7)) * 8),         \
             &Vl[BS][j * 512]);                                                         \
    }                                                                                   \
  } while (0)

  for (int pass = 0; pass < 2; pass++){
    const int qb = pass ? bx : (15 - bx);      // long tile first
    const int q0 = qb * 128;
    const int qw = q0 + w * 32;
    const int myq = qw + q31;
    const ushort* Qp = Q + ((size_t)(b * 32 + h) * 2048 + myq) * 128;
    short8 qf[8];
    #pragma unroll
    for (int s = 0; s < 8; s++) qf[s] = *(const short8*)(Qp + s * 16 + hi * 8);
    f32x16 o[4] = {};
    float m_r = -INFINITY, l_r = 0.f;
    const int nt = 2 * qb + 2;

    STAGE(0, 0);
    for (int kt = 0; kt < nt; kt++){
      const int cur = kt & 1;
      if (kt + 1 < nt){
        STAGE(kt + 1, cur ^ 1);
        asm volatile("s_waitcnt vmcnt(8)" ::: "memory");
      } else {
        asm volatile("s_waitcnt vmcnt(0)" ::: "memory");
      }
      __builtin_amdgcn_s_barrier();
      asm volatile("" ::: "memory");
      f32x16 sa0 = {}, sa1 = {};
      __builtin_amdgcn_s_setprio(1);
      #pragma unroll
      for (int s = 0; s < 8; s++){
        short8 a0 = *(const short8*)&Kl[cur][q31 * 128 + (((2 * s + hi) ^ swz) * 8)];
        short8 a1 = *(const short8*)&Kl[cur][(32 + q31) * 128 + (((2 * s + hi) ^ swz) * 8)];
        sa0 = mfma32(a0, qf[s], sa0);
        sa1 = mfma32(a1, qf[s], sa1);
      }
      __builtin_amdgcn_s_setprio(0);
      if (kt >= 2 * qb){
        #pragma unroll
        for (int r = 0; r < 16; r++){
          int krel = (r & 3) + 8 * (r >> 2) + 4 * hi;
          if (kt * 64 + krel > myq)      sa0[r] = -INFINITY;
          if (kt * 64 + 32 + krel > myq) sa1[r] = -INFINITY;
        }
      }
      float mx = fmaxf(sa0[0], sa1[0]);
      #pragma unroll
      for (int r = 1; r < 16; r++) mx = fmaxf(mx, fmaxf(sa0[r], sa1[r]));
      mx = fmaxf(mx, __shfl_xor(mx, 32));
      if (!__all(mx - m_r <= 8.f)){
        float mn = fmaxf(m_r, mx);
        float al = ex2(m_r - mn);
        m_r = mn; l_r *= al;
        #pragma unroll
        for (int r = 0; r < 16; r++){
          float alq = __shfl(al, (r & 3) + 8 * (r >> 2) + 4 * hi);
          o[0][r] *= alq; o[1][r] *= alq; o[2][r] *= alq; o[3][r] *= alq;
        }
      }
      float rsum = 0.f;
      #pragma unroll
      for (int r = 0; r < 16; r++){
        sa0[r] = ex2(sa0[r] - m_r);
        sa1[r] = ex2(sa1[r] - m_r);
        rsum += sa0[r] + sa1[r];
      }
      rsum += __shfl_xor(rsum, 32);
      l_r += rsum;
      uint pk0[8], pk1[8];
      #pragma unroll
      for (int t = 0; t < 8; t++){
        pk0[t] = cvtpk(sa0[2 * t], sa0[2 * t + 1]);
        pk1[t] = cvtpk(sa1[2 * t], sa1[2 * t + 1]);
      }
      __builtin_amdgcn_s_setprio(1);
      #pragma unroll
      for (int sub = 0; sub < 2; sub++){
        #pragma unroll
        for (int kc = 0; kc < 2; kc++){
          uint p0 = sub ? pk1[4 * kc]     : pk0[4 * kc];
          uint p1 = sub ? pk1[4 * kc + 1] : pk0[4 * kc + 1];
          uint p2 = sub ? pk1[4 * kc + 2] : pk0[4 * kc + 2];
          uint p3 = sub ? pk1[4 * kc + 3] : pk0[4 * kc + 3];
          uint2v r02 = __builtin_amdgcn_permlane32_swap(p0, p2, false, false);
          uint2v r13 = __builtin_amdgcn_permlane32_swap(p1, p3, false, false);
          union { uint u[4]; short8 v; } Af;
          Af.u[0] = r02[0]; Af.u[1] = r13[0]; Af.u[2] = r02[1]; Af.u[3] = r13[1];
          #pragma unroll
          for (int dc = 0; dc < 4; dc++){
            short8 vf = *(const short8*)&Vl[cur][(dc * 32 + q31) * 64 + (((4 * sub + 2 * kc + hi) ^ swz) * 8)];
            o[dc] = mfma32(Af.v, vf, o[dc]);
          }
        }
      }
      __builtin_amdgcn_s_setprio(0);
      asm volatile("" ::: "memory");
      __builtin_amdgcn_s_barrier();
    }
    float invl = 1.0f / l_r;
    ushort* Cp = ctx + (size_t)(b * 2048 + qw) * 4096 + (size_t)h * 128;
    #pragma unroll
    for (int r = 0; r < 16; r++){
      int qrel = (r & 3) + 8 * (r >> 2) + 4 * hi;
      float inv = __shfl(invl, qrel);
      #pragma unroll
      for (int dc = 0; dc < 4; dc++)
        Cp[(size_t)qrel * 4096 + dc * 32 + q31] = f2bf(o[dc][r] * inv);
    }
  }
  #undef STAGE
}

extern "C" void kernel_launch(void* const* d_in, const int* in_sizes, int n_in,
                              void* d_out, int out_size, void* d_ws, size_t ws_size,
                              hipStream_t stream){
  const float* x    = (const float*)d_in[0];
  // d_in[1] = mask (causality implemented directly)
  const float* cosT = (const float*)d_in[2];
  const float* sinT = (const float*)d_in[3];
  const float* Wq   = (const float*)d_in[4];
  const float* bq   = (const float*)d_in[5];
  const float* Wk   = (const float*)d_in[6];
  const float* bk   = (const float*)d_in[7];
  const float* Wv   = (const float*)d_in[8];
  const float* bv   = (const float*)d_in[9];
  const float* Wo   = (const float*)d_in[10];
  const float* qs   = (const float*)d_in[11];
  const float* ksc  = (const float*)d_in[12];
  float* out = (float*)d_out;
  char* ws = (char*)d_ws;

  ushort* xb    = (ushort*)(ws + 0);           // 4096x2048 bf16
  ushort* wtqkv = (ushort*)(ws + 16777216);    // 6144x2048 bf16
  float*  biasq = (float* )(ws + 41943040);    // 6144 f32
  ushort* qkv   = (ushort*)(ws + 41967616);    // 4096x6144 bf16 (dead after norm_rope)
  ushort* qb_   = (ushort*)(ws + 92299264);    // B,H,S,D bf16   (dead after flash)
  ushort* kb_   = (ushort*)(ws + 125853696);   // B,KV,S,D bf16
  ushort* vtb   = (ushort*)(ws + 134242304);   // B,KV,D,S bf16
  ushort* ctx   = (ushort*)(ws + 142630912);   // 4096x4096 bf16
  ushort* wot   = (ushort*)(ws + 176185344);   // 2048x4096 bf16
  // out-proj split-K partials (f32 4096x2048 each) alias qkv/qb_ (dead by then)
  float* part   = (float*)(ws + 41967616);     // 2 x 33.55 MB

  cvt_bf16_kernel<<<8192, 256, 0, stream>>>(x, xb, 2097152);
  transpose_cvt_kernel<<<dim3(128, 64), dim3(32, 8), 0, stream>>>(Wq, wtqkv, 2048, 4096);
  transpose_cvt_kernel<<<dim3(32, 64),  dim3(32, 8), 0, stream>>>(Wk, wtqkv + (size_t)4096 * 2048, 2048, 1024);
  transpose_cvt_kernel<<<dim3(32, 64),  dim3(32, 8), 0, stream>>>(Wv, wtqkv + (size_t)5120 * 2048, 2048, 1024);
  transpose_cvt_kernel<<<dim3(64, 128), dim3(32, 8), 0, stream>>>(Wo, wot, 4096, 2048);
  bias_concat_kernel<<<24, 256, 0, stream>>>(bq, bk, bv, biasq);

  gemm8p_kernel<ushort><<<dim3(384, 1), 512, 0, stream>>>(xb, wtqkv, biasq, qkv, 4096, 6144, 2048, 2048);
  norm_rope_kernel<<<49152, 256, 0, stream>>>(qkv, cosT, sinT, qs, ksc, qb_, kb_, vtb);
  flash_kernel<<<dim3(8, 64), 256, 0, stream>>>(qb_, kb_, vtb, ctx);
  gemm8p_kernel<float><<<dim3(128, 2), 512, 0, stream>>>(ctx, wot, nullptr, part, 4096, 2048, 4096, 2048);
  addk_kernel<<<8192, 256, 0, stream>>>(part, part + (size_t)4096 * 2048, out, 2097152);
}

// Round 15
// 374.243 us; speedup vs baseline: 1.1467x; 1.1467x over previous
//
#include <hip/hip_runtime.h>

typedef short short8 __attribute__((ext_vector_type(8)));
typedef float f32x4 __attribute__((ext_vector_type(4)));
typedef float f32x16 __attribute__((ext_vector_type(16)));
typedef unsigned int uint2v __attribute__((ext_vector_type(2)));

// ---------- helpers ----------
static __device__ __forceinline__ ushort f2bf(float f){
  union { float f; uint u; } cv; cv.f = f;
  uint u = cv.u;
  uint r = (u + 0x7fffu + ((u >> 16) & 1u)) >> 16;
  return (ushort)r;
}
static __device__ __forceinline__ float bf2f(ushort h){
  union { uint u; float f; } cv; cv.u = ((uint)h) << 16; return cv.f;
}
static __device__ __forceinline__ f32x4 mfma16(short8 a, short8 b, f32x4 c){
  return __builtin_amdgcn_mfma_f32_16x16x32_bf16(a, b, c, 0, 0, 0);
}
static __device__ __forceinline__ f32x16 mfma32(short8 a, short8 b, f32x16 c){
  return __builtin_amdgcn_mfma_f32_32x32x16_bf16(a, b, c, 0, 0, 0);
}
static __device__ __forceinline__ float ex2(float x){
  float r; asm("v_exp_f32 %0, %1" : "=v"(r) : "v"(x)); return r;
}
static __device__ __forceinline__ uint cvtpk(float lo, float hi){
  uint r; asm("v_cvt_pk_bf16_f32 %0, %1, %2" : "=v"(r) : "v"(lo), "v"(hi)); return r;
}
static __device__ __forceinline__ void glds16(const void* g, const void* l){
  __builtin_amdgcn_global_load_lds((const __attribute__((address_space(1))) void*)g,
                                   (__attribute__((address_space(3))) void*)l, 16, 0, 0);
}
static __device__ __forceinline__ void store_out(float* p, float v){ *p = v; }
static __device__ __forceinline__ void store_out(ushort* p, float v){ *p = f2bf(v); }
// bijective XCD-aware block swizzle (m204 form)
static __device__ __forceinline__ int xcd_swizzle(int flat, int nwg){
  int q = nwg >> 3, r = nwg & 7;
  int xcd = flat & 7, idx = flat >> 3;
  return (xcd < r) ? xcd * (q + 1) + idx : r * (q + 1) + (xcd - r) * q + idx;
}

// ---------- elementwise f32 -> bf16 ----------
__global__ void cvt_bf16_kernel(const float* __restrict__ x, ushort* __restrict__ y, int n4){
  int i = blockIdx.x * 256 + threadIdx.x;
  if (i < n4){
    float4 v = reinterpret_cast<const float4*>(x)[i];
    ushort4 o; o.x = f2bf(v.x); o.y = f2bf(v.y); o.z = f2bf(v.z); o.w = f2bf(v.w);
    reinterpret_cast<ushort4*>(y)[i] = o;
  }
}

// ---------- transpose + cast: W (K x N) f32 -> WT (N x K) bf16 ----------
__global__ void transpose_cvt_kernel(const float* __restrict__ W, ushort* __restrict__ WT, int K, int N){
  __shared__ float tile[32][33];
  int n0 = blockIdx.x * 32, k0 = blockIdx.y * 32;
  int tx = threadIdx.x, ty = threadIdx.y; // block (32,8)
  #pragma unroll
  for (int i = 0; i < 4; i++){ int r = ty + i * 8; tile[r][tx] = W[(size_t)(k0 + r) * N + n0 + tx]; }
  __syncthreads();
  #pragma unroll
  for (int i = 0; i < 4; i++){ int r = ty + i * 8; WT[(size_t)(n0 + r) * K + k0 + tx] = f2bf(tile[tx][r]); }
}

// ---------- concat qkv bias ----------
__global__ void bias_concat_kernel(const float* __restrict__ bq, const float* __restrict__ bk,
                                   const float* __restrict__ bv, float* __restrict__ out){
  int i = blockIdx.x * 256 + threadIdx.x;
  if (i < 6144) out[i] = (i < 4096) ? bq[i] : ((i < 5120) ? bk[i - 4096] : bv[i - 5120]);
}

// ---------- 128x128 GEMM, BK=64, 2 blocks/CU: C = A(M,K) * BT(N,K)^T + bias ----------
// 4 waves 2x2, per-wave 64x64 (acc f32x4[4][4]). Double-buffered 64 KB LDS ->
// 2 co-resident blocks/CU (cross-block overlap fills stalls, m114). BK=64:
// 8x16B chunks per 128B row -> full 32-bank coverage (r9-measured 0 conflicts;
// BK=32's 4-chunk geometry idles banks 16-31 -> r11's 1.26e7 conflicts).
// Per K-tile: stage t+1 (8 glds16/thread) -> counted vmcnt(8) (t's loads done,
// t+1's in flight; never drains mid-loop) -> fenced barrier -> 16 ds_read_b128
// -> setprio'd 32-MFMA cluster -> fenced barrier (WAR before restage).
// Swizzle: source chunk c^(row&7), read pos (ks*4+lk)^(lm&7) (proven 0-conflict).
template<typename OutT>
__global__ __launch_bounds__(256, 2)
void gemm_c2_kernel(const ushort* __restrict__ A, const ushort* __restrict__ BT,
                    const float* __restrict__ bias, OutT* __restrict__ C,
                    int M, int N, int K){
  __shared__ __align__(16) ushort As[2][128 * 64];
  __shared__ __align__(16) ushort Bs[2][128 * 64];
  const int nbx = N >> 7;
  const int nwg = nbx * (M >> 7);
  const int wg = xcd_swizzle(blockIdx.x, nwg);
  const int m0 = (wg / nbx) * 128, n0 = (wg % nbx) * 128;
  const int tid = threadIdx.x, w = tid >> 6, l = tid & 63, lm = l & 15, lk = l >> 4;
  const int wr = w >> 1, wc = w & 1;          // 2x2 waves, per-wave 64x64
  const int nt = K >> 6;

#define STAGE_T(TK, BUF) do{                                                               \
    _Pragma("unroll")                                                                      \
    for (int r = 0; r < 4; r++){                                                           \
      int s = r * 256 + tid, row = s >> 3, ch = (s & 7) ^ (row & 7);                       \
      glds16(A + (size_t)(m0 + row) * K + (size_t)(TK) * 64 + ch * 8, &As[BUF][s * 8]);    \
    }                                                                                      \
    _Pragma("unroll")                                                                      \
    for (int r = 0; r < 4; r++){                                                           \
      int s = r * 256 + tid, row = s >> 3, ch = (s & 7) ^ (row & 7);                       \
      glds16(BT + (size_t)(n0 + row) * K + (size_t)(TK) * 64 + ch * 8, &Bs[BUF][s * 8]);   \
    }                                                                                      \
  }while(0)

  f32x4 acc[4][4] = {};
  STAGE_T(0, 0);
  for (int t = 0; t < nt; t++){
    const int cur = t & 1;
    if (t + 1 < nt){
      STAGE_T(t + 1, cur ^ 1);
      asm volatile("s_waitcnt vmcnt(8)" ::: "memory");
    } else {
      asm volatile("s_waitcnt vmcnt(0)" ::: "memory");
    }
    __builtin_amdgcn_s_barrier();
    asm volatile("" ::: "memory");
    short8 af[4][2], bf[4][2];
    #pragma unroll
    for (int mi = 0; mi < 4; mi++)
      #pragma unroll
      for (int ks = 0; ks < 2; ks++)
        af[mi][ks] = *(const short8*)&As[cur][(wr * 64 + mi * 16 + lm) * 64 + (((ks * 4 + lk) ^ (lm & 7)) * 8)];
    #pragma unroll
    for (int ni = 0; ni < 4; ni++)
      #pragma unroll
      for (int ks = 0; ks < 2; ks++)
        bf[ni][ks] = *(const short8*)&Bs[cur][(wc * 64 + ni * 16 + lm) * 64 + (((ks * 4 + lk) ^ (lm & 7)) * 8)];
    __builtin_amdgcn_s_setprio(1);
    #pragma unroll
    for (int mi = 0; mi < 4; mi++)
      #pragma unroll
      for (int ni = 0; ni < 4; ni++)
        #pragma unroll
        for (int ks = 0; ks < 2; ks++)
          acc[mi][ni] = mfma16(af[mi][ks], bf[ni][ks], acc[mi][ni]);
    __builtin_amdgcn_s_setprio(0);
    asm volatile("" ::: "memory");
    __builtin_amdgcn_s_barrier();
  }
#undef STAGE_T
  // ---- epilogue ----
  #pragma unroll
  for (int mi = 0; mi < 4; mi++)
    #pragma unroll
    for (int ni = 0; ni < 4; ni++){
      int col = n0 + wc * 64 + ni * 16 + lm;
      float bb = bias ? bias[col] : 0.0f;
      #pragma unroll
      for (int r = 0; r < 4; r++){
        int row = m0 + wr * 64 + mi * 16 + lk * 4 + r;
        store_out(&C[(size_t)row * N + col], acc[mi][ni][r] + bb);
      }
    }
}

// ---------- RMSNorm + RoPE + relayout ----------
#define QSCL2 0.12752016f
__global__ __launch_bounds__(256) void norm_rope_kernel(const ushort* __restrict__ qkv,
    const float* __restrict__ cosT, const float* __restrict__ sinT,
    const float* __restrict__ qs, const float* __restrict__ ksc,
    ushort* __restrict__ qo, ushort* __restrict__ ko, ushort* __restrict__ vto){
  int slot = blockIdx.x * 4 + (threadIdx.x >> 6);
  int lane = threadIdx.x & 63;
  int row = slot / 48, c = slot % 48;      // row = b*S + s
  int b = row >> 11, s = row & 2047;
  size_t base = (size_t)row * 6144 + c * 128;
  float e1 = bf2f(qkv[base + lane]);
  float e2 = bf2f(qkv[base + lane + 64]);
  if (c < 40){
    float ss = e1 * e1 + e2 * e2;
    #pragma unroll
    for (int m = 1; m < 64; m <<= 1) ss += __shfl_xor(ss, m);
    float rs = rsqrtf(ss * (1.0f / 128.0f) + 1e-6f);
    const float* sc = (c < 32) ? qs : ksc;
    float n1 = e1 * rs * sc[lane], n2 = e2 * rs * sc[lane + 64];
    float c1 = cosT[s * 128 + lane],      s1 = sinT[s * 128 + lane];
    float c2 = cosT[s * 128 + lane + 64], s2 = sinT[s * 128 + lane + 64];
    float o1 = n1 * c1 - n2 * s1;
    float o2 = n2 * c2 + n1 * s2;
    if (c < 32){
      size_t ob = ((size_t)(b * 32 + c) * 2048 + s) * 128;
      qo[ob + lane] = f2bf(o1 * QSCL2); qo[ob + lane + 64] = f2bf(o2 * QSCL2);
    } else {
      int kv = c - 32;
      size_t ob = ((size_t)(b * 8 + kv) * 2048 + s) * 128;
      ko[ob + lane] = f2bf(o1); ko[ob + lane + 64] = f2bf(o2);
    }
  } else {
    int kv = c - 40;
    size_t ob = (size_t)(b * 8 + kv) * 128;
    vto[(ob + lane) * 2048 + s]      = f2bf(e1);
    vto[(ob + lane + 64) * 2048 + s] = f2bf(e2);
  }
}

// ---------- causal GQA flash attention: 32x32 MFMA, QBLK=128, KVBLK=64 ----------
__global__ __launch_bounds__(256, 2) void flash_kernel(const ushort* __restrict__ Q, const ushort* __restrict__ Kg,
    const ushort* __restrict__ VTg, ushort* __restrict__ ctx){
  __shared__ ushort Kl[2][64 * 128];
  __shared__ ushort Vl[2][128 * 64];
  const int bh = blockIdx.y, b = bh >> 5, h = bh & 31, kvh = h >> 2;
  const int bx = blockIdx.x;
  const int tid = threadIdx.x, w = tid >> 6, l = tid & 63;
  const int q31 = l & 31, hi = l >> 5, swz = q31 & 7;
  const ushort* Kbase = Kg  + (size_t)(b * 8 + kvh) * 2048 * 128;
  const ushort* Vbase = VTg + (size_t)(b * 8 + kvh) * 128 * 2048;
  const int krow = l >> 4, kcol = l & 15;
  const int vrow = l >> 3, vcol = l & 7;

  #define STAGE(KT, BS) do {                                                            \
    _Pragma("unroll")                                                                   \
    for (int i2 = 0; i2 < 4; i2++){                                                     \
      int i = w * 4 + i2; int row = i * 4 + krow;                                       \
      glds16(Kbase + (size_t)((KT) * 64 + row) * 128 + ((kcol ^ (row & 7)) * 8),        \
             &Kl[BS][i * 512]);                                                         \
    }                                                                                   \
    _Pragma("unroll")                                                                   \
    for (int j2 = 0; j2 < 4; j2++){                                                     \
      int j = w * 4 + j2; int row = j * 8 + vrow;                                       \
      glds16(Vbase + (size_t)row * 2048 + (KT) * 64 + ((vcol ^ (row & 7)) * 8),         \
             &Vl[BS][j * 512]);                                                         \
    }                                                                                   \
  } while (0)

  for (int pass = 0; pass < 2; pass++){
    const int qb = pass ? bx : (15 - bx);      // long tile first
    const int q0 = qb * 128;
    const int qw = q0 + w * 32;
    const int myq = qw + q31;
    const ushort* Qp = Q + ((size_t)(b * 32 + h) * 2048 + myq) * 128;
    short8 qf[8];
    #pragma unroll
    for (int s = 0; s < 8; s++) qf[s] = *(const short8*)(Qp + s * 16 + hi * 8);
    f32x16 o[4] = {};
    float m_r = -INFINITY, l_r = 0.f;
    const int nt = 2 * qb + 2;

    STAGE(0, 0);
    for (int kt = 0; kt < nt; kt++){
      const int cur = kt & 1;
      if (kt + 1 < nt){
        STAGE(kt + 1, cur ^ 1);
        asm volatile("s_waitcnt vmcnt(8)" ::: "memory");
      } else {
        asm volatile("s_waitcnt vmcnt(0)" ::: "memory");
      }
      __builtin_amdgcn_s_barrier();
      asm volatile("" ::: "memory");
      f32x16 sa0 = {}, sa1 = {};
      __builtin_amdgcn_s_setprio(1);
      #pragma unroll
      for (int s = 0; s < 8; s++){
        short8 a0 = *(const short8*)&Kl[cur][q31 * 128 + (((2 * s + hi) ^ swz) * 8)];
        short8 a1 = *(const short8*)&Kl[cur][(32 + q31) * 128 + (((2 * s + hi) ^ swz) * 8)];
        sa0 = mfma32(a0, qf[s], sa0);
        sa1 = mfma32(a1, qf[s], sa1);
      }
      __builtin_amdgcn_s_setprio(0);
      if (kt >= 2 * qb){
        #pragma unroll
        for (int r = 0; r < 16; r++){
          int krel = (r & 3) + 8 * (r >> 2) + 4 * hi;
          if (kt * 64 + krel > myq)      sa0[r] = -INFINITY;
          if (kt * 64 + 32 + krel > myq) sa1[r] = -INFINITY;
        }
      }
      float mx = fmaxf(sa0[0], sa1[0]);
      #pragma unroll
      for (int r = 1; r < 16; r++) mx = fmaxf(mx, fmaxf(sa0[r], sa1[r]));
      mx = fmaxf(mx, __shfl_xor(mx, 32));
      if (!__all(mx - m_r <= 8.f)){
        float mn = fmaxf(m_r, mx);
        float al = ex2(m_r - mn);
        m_r = mn; l_r *= al;
        #pragma unroll
        for (int r = 0; r < 16; r++){
          float alq = __shfl(al, (r & 3) + 8 * (r >> 2) + 4 * hi);
          o[0][r] *= alq; o[1][r] *= alq; o[2][r] *= alq; o[3][r] *= alq;
        }
      }
      float rsum = 0.f;
      #pragma unroll
      for (int r = 0; r < 16; r++){
        sa0[r] = ex2(sa0[r] - m_r);
        sa1[r] = ex2(sa1[r] - m_r);
        rsum += sa0[r] + sa1[r];
      }
      rsum += __shfl_xor(rsum, 32);
      l_r += rsum;
      uint pk0[8], pk1[8];
      #pragma unroll
      for (int t = 0; t < 8; t++){
        pk0[t] = cvtpk(sa0[2 * t], sa0[2 * t + 1]);
        pk1[t] = cvtpk(sa1[2 * t], sa1[2 * t + 1]);
      }
      __builtin_amdgcn_s_setprio(1);
      #pragma unroll
      for (int sub = 0; sub < 2; sub++){
        #pragma unroll
        for (int kc = 0; kc < 2; kc++){
          uint p0 = sub ? pk1[4 * kc]     : pk0[4 * kc];
          uint p1 = sub ? pk1[4 * kc + 1] : pk0[4 * kc + 1];
          uint p2 = sub ? pk1[4 * kc + 2] : pk0[4 * kc + 2];
          uint p3 = sub ? pk1[4 * kc + 3] : pk0[4 * kc + 3];
          uint2v r02 = __builtin_amdgcn_permlane32_swap(p0, p2, false, false);
          uint2v r13 = __builtin_amdgcn_permlane32_swap(p1, p3, false, false);
          union { uint u[4]; short8 v; } Af;
          Af.u[0] = r02[0]; Af.u[1] = r13[0]; Af.u[2] = r02[1]; Af.u[3] = r13[1];
          #pragma unroll
          for (int dc = 0; dc < 4; dc++){
            short8 vf = *(const short8*)&Vl[cur][(dc * 32 + q31) * 64 + (((4 * sub + 2 * kc + hi) ^ swz) * 8)];
            o[dc] = mfma32(Af.v, vf, o[dc]);
          }
        }
      }
      __builtin_amdgcn_s_setprio(0);
      asm volatile("" ::: "memory");
      __builtin_amdgcn_s_barrier();
    }
    float invl = 1.0f / l_r;
    ushort* Cp = ctx + (size_t)(b * 2048 + qw) * 4096 + (size_t)h * 128;
    #pragma unroll
    for (int r = 0; r < 16; r++){
      int qrel = (r & 3) + 8 * (r >> 2) + 4 * hi;
      float inv = __shfl(invl, qrel);
      #pragma unroll
      for (int dc = 0; dc < 4; dc++)
        Cp[(size_t)qrel * 4096 + dc * 32 + q31] = f2bf(o[dc][r] * inv);
    }
  }
  #undef STAGE
}

extern "C" void kernel_launch(void* const* d_in, const int* in_sizes, int n_in,
                              void* d_out, int out_size, void* d_ws, size_t ws_size,
                              hipStream_t stream){
  const float* x    = (const float*)d_in[0];
  // d_in[1] = mask (causality implemented directly)
  const float* cosT = (const float*)d_in[2];
  const float* sinT = (const float*)d_in[3];
  const float* Wq   = (const float*)d_in[4];
  const float* bq   = (const float*)d_in[5];
  const float* Wk   = (const float*)d_in[6];
  const float* bk   = (const float*)d_in[7];
  const float* Wv   = (const float*)d_in[8];
  const float* bv   = (const float*)d_in[9];
  const float* Wo   = (const float*)d_in[10];
  const float* qs   = (const float*)d_in[11];
  const float* ksc  = (const float*)d_in[12];
  float* out = (float*)d_out;
  char* ws = (char*)d_ws;

  ushort* xb    = (ushort*)(ws + 0);           // 4096x2048 bf16
  ushort* wtqkv = (ushort*)(ws + 16777216);    // 6144x2048 bf16
  float*  biasq = (float* )(ws + 41943040);    // 6144 f32
  ushort* qkv   = (ushort*)(ws + 41967616);    // 4096x6144 bf16
  ushort* qb_   = (ushort*)(ws + 92299264);    // B,H,S,D bf16
  ushort* kb_   = (ushort*)(ws + 125853696);   // B,KV,S,D bf16
  ushort* vtb   = (ushort*)(ws + 134242304);   // B,KV,D,S bf16
  ushort* ctx   = (ushort*)(ws + 142630912);   // 4096x4096 bf16
  ushort* wot   = (ushort*)(ws + 176185344);   // 2048x4096 bf16

  cvt_bf16_kernel<<<8192, 256, 0, stream>>>(x, xb, 2097152);
  transpose_cvt_kernel<<<dim3(128, 64), dim3(32, 8), 0, stream>>>(Wq, wtqkv, 2048, 4096);
  transpose_cvt_kernel<<<dim3(32, 64),  dim3(32, 8), 0, stream>>>(Wk, wtqkv + (size_t)4096 * 2048, 2048, 1024);
  transpose_cvt_kernel<<<dim3(32, 64),  dim3(32, 8), 0, stream>>>(Wv, wtqkv + (size_t)5120 * 2048, 2048, 1024);
  transpose_cvt_kernel<<<dim3(64, 128), dim3(32, 8), 0, stream>>>(Wo, wot, 4096, 2048);
  bias_concat_kernel<<<24, 256, 0, stream>>>(bq, bk, bv, biasq);

  // QKV: 128x128 tile, grid 32x48 = 1536 (3 exact rounds at 2 blocks/CU)
  gemm_c2_kernel<ushort><<<1536, 256, 0, stream>>>(xb, wtqkv, biasq, qkv, 4096, 6144, 2048);
  norm_rope_kernel<<<49152, 256, 0, stream>>>(qkv, cosT, sinT, qs, ksc, qb_, kb_, vtb);
  flash_kernel<<<dim3(8, 64), 256, 0, stream>>>(qb_, kb_, vtb, ctx);
  // out-proj: grid 32x16 = 512 = exactly 2 blocks/CU, one round
  gemm_c2_kernel<float><<<512, 256, 0, stream>>>(ctx, wot, nullptr, out, 4096, 2048, 4096);
}